// Round 1
// baseline (109.852 us; speedup 1.0000x reference)
//
#include <hip/hip_runtime.h>
#include <math.h>

// Problem geometry (fixed by reference setup_inputs)
#define GG 52
#define AA 3
#define BB 16
#define DD 85                    // 5 + 80 classes
#define NCELL (GG*GG*AA)         // 8112 cells per batch
#define EBAT (NCELL*DD)          // 689520 elements per batch (divisible by 4)
#define VECS (EBAT/4)            // 172380 float4s per batch
#define BPB 128                  // blocks per batch
#define NTHREADS 256

__device__ __forceinline__ float sigf(float x){ return 1.0f/(1.0f+expf(-x)); }

// -(t*max(log p,-100) + (1-t)*max(log1p(-p),-100)), p already sigmoid'd
__device__ __forceinline__ float bcef(float s, float t){
  float lp  = fmaxf(logf(s),    -100.0f);
  float l1p = fmaxf(log1pf(-s), -100.0f);
  return -(t*lp + (1.0f - t)*l1p);
}

// Partials per block: [pid][0]=S1 (xy+wh weighted sq), [1]=S2 (sum obj),
//                     [2]=cls-bce sum, [3]=obj-bce sum
__global__ __launch_bounds__(NTHREADS) void yolo_main(
    const float* __restrict__ yp, const float* __restrict__ yt,
    const float* __restrict__ anch, float* __restrict__ part)
{
  const int b = blockIdx.y;
  const float* __restrict__ ypb = yp + (size_t)b * EBAT;
  const float* __restrict__ ytb = yt + (size_t)b * EBAT;

  const float a00=anch[0], a01=anch[1], a10=anch[2], a11=anch[3], a20=anch[4], a21=anch[5];

  float s1 = 0.f, s2 = 0.f, cb = 0.f, ob = 0.f;

  for (int v = blockIdx.x * NTHREADS + threadIdx.x; v < VECS; v += BPB * NTHREADS) {
    float4 p4 = ((const float4*)ypb)[v];
    float4 t4 = ((const float4*)ytb)[v];
    int i0 = v * 4;
    #pragma unroll
    for (int k = 0; k < 4; ++k) {
      float p = (&p4.x)[k];
      float t = (&t4.x)[k];
      int i    = i0 + k;
      int cell = i / DD;              // cell within batch
      int c    = i - cell * DD;       // channel 0..84
      float s  = sigf(p);
      if (c >= 5) {                   // class BCE (global mean numerator)
        cb += bcef(s, t);
      } else if (c == 4) {            // objectness BCE + obj sum
        ob += bcef(s, t);
        s2 += t;
      } else {                        // box regression, weighted by obj of this cell
        float obj = ytb[cell * DD + 4];
        float tgt;
        if (c < 2) {
          int gi = cell / (GG * AA);        // meshgrid 'ij': dim-1 index for ch0
          int gj = (cell / AA) % GG;        // dim-2 index for ch1
          tgt = t * (float)GG - (float)(c == 0 ? gi : gj);
        } else {
          int a = cell - (cell / AA) * AA;  // anchor index
          float anc = (c == 2) ? (a == 0 ? a00 : (a == 1 ? a10 : a20))
                               : (a == 0 ? a01 : (a == 1 ? a11 : a21));
          float r = t / anc;
          tgt = (r > 0.0f) ? logf(r) : 0.0f;
        }
        float d = tgt - s;
        s1 += d * d * obj;
      }
    }
  }

  // wave (64-lane) shuffle reduce
  for (int off = 32; off > 0; off >>= 1) {
    s1 += __shfl_down(s1, off);
    s2 += __shfl_down(s2, off);
    cb += __shfl_down(cb, off);
    ob += __shfl_down(ob, off);
  }
  __shared__ float lds[NTHREADS / 64][4];
  int lane = threadIdx.x & 63, wid = threadIdx.x >> 6;
  if (lane == 0) { lds[wid][0] = s1; lds[wid][1] = s2; lds[wid][2] = cb; lds[wid][3] = ob; }
  __syncthreads();
  if (threadIdx.x == 0) {
    float r0 = 0, r1 = 0, r2 = 0, r3 = 0;
    #pragma unroll
    for (int w = 0; w < NTHREADS / 64; ++w) {
      r0 += lds[w][0]; r1 += lds[w][1]; r2 += lds[w][2]; r3 += lds[w][3];
    }
    int pid = b * BPB + blockIdx.x;
    part[pid * 4 + 0] = r0;
    part[pid * 4 + 1] = r1;
    part[pid * 4 + 2] = r2;
    part[pid * 4 + 3] = r3;
  }
}

__global__ __launch_bounds__(256) void yolo_fin(
    const float* __restrict__ part, float* __restrict__ out)
{
  const int tid = threadIdx.x;
  // global scalars: sum cls-bce and obj-bce over all 2048 block partials
  float c = 0.f, o = 0.f;
  for (int i = tid; i < BB * BPB; i += 256) { c += part[i * 4 + 2]; o += part[i * 4 + 3]; }
  for (int off = 32; off > 0; off >>= 1) { c += __shfl_down(c, off); o += __shfl_down(o, off); }
  __shared__ float lds[4][2];
  int lane = tid & 63, wid = tid >> 6;
  if (lane == 0) { lds[wid][0] = c; lds[wid][1] = o; }
  __syncthreads();
  __shared__ float cs, os;
  if (tid == 0) {
    cs = lds[0][0] + lds[1][0] + lds[2][0] + lds[3][0];
    os = lds[0][1] + lds[1][1] + lds[2][1] + lds[3][1];
  }
  __syncthreads();
  if (tid < BB) {
    float s1 = 0.f, s2 = 0.f;
    for (int j = 0; j < BPB; ++j) {
      s1 += part[(tid * BPB + j) * 4 + 0];
      s2 += part[(tid * BPB + j) * 4 + 1];
    }
    const float ncls = (float)BB * (float)NCELL * 80.0f;  // 10,383,360 (< 2^24, exact)
    const float nobj = (float)BB * (float)NCELL;          // 129,792
    out[tid] = 2.0f * s1 + (0.5f * cs / ncls + os / nobj) * s2;
  }
}

extern "C" void kernel_launch(void* const* d_in, const int* in_sizes, int n_in,
                              void* d_out, int out_size, void* d_ws, size_t ws_size,
                              hipStream_t stream) {
  const float* yp   = (const float*)d_in[0];   // y_pred (16,52,52,3,85)
  const float* yt   = (const float*)d_in[1];   // y_true (16,52,52,3,85)
  const float* anch = (const float*)d_in[2];   // (3,2)
  float* out  = (float*)d_out;                 // (16,)
  float* part = (float*)d_ws;                  // 2048*4 floats = 32 KB scratch

  dim3 grid(BPB, BB);
  yolo_main<<<grid, NTHREADS, 0, stream>>>(yp, yt, anch, part);
  yolo_fin<<<1, 256, 0, stream>>>(part, out);
}

// Round 2
// 29.534 us; speedup vs baseline: 3.7196x; 3.7196x over previous
//
#include <hip/hip_runtime.h>
#include <math.h>

// Geometry fixed by reference setup_inputs
#define GG 52
#define AA 3
#define BB 16
#define DD 85                      // 5 + 80 classes
#define NCELL (GG*GG*AA)           // 8112 cells per batch
#define EBAT (NCELL*DD)            // 689520 elems per batch
#define TOTV ((BB*EBAT)/4)         // 2,758,080 float4s total (EBAT*BB divisible by 4)
#define NA_BLK 2048                // pass-A blocks (uniform BCE stream)
#define NB_BLK_PB 32               // pass-B blocks per batch (8192 threads >= 8112 cells)
#define NB_BLK (NB_BLK_PB*BB)      // 512
#define NTHREADS 256
#define LN2 0.69314718055994530942f

// ws layout (floats): [0 .. NA_BLK*2)              pass-A partials {sumH, sumLog2}
//                     [NA_BLK*2 .. +NB_BLK*4)      pass-B partials {s1, s2, bce5, bceObj}

__device__ __forceinline__ float fast_sig(float x) {
  float u = __expf(-fabsf(x));                 // exp(-|x|)
  float r = __builtin_amdgcn_rcpf(1.0f + u);   // 1/(1+u), ~1ulp
  return x >= 0.0f ? r : u * r;
}
// bce(sigmoid(x), t) = max(x,0) - x*t + log1p(exp(-|x|))
__device__ __forceinline__ float fast_bce(float x, float t) {
  float u = __expf(-fabsf(x));
  return fmaxf(x, 0.0f) - x * t + LN2 * __log2f(1.0f + u);
}

__device__ __forceinline__ void block_reduce4(float v0, float v1, float v2, float v3,
                                              float* dst) {
  for (int off = 32; off > 0; off >>= 1) {
    v0 += __shfl_down(v0, off); v1 += __shfl_down(v1, off);
    v2 += __shfl_down(v2, off); v3 += __shfl_down(v3, off);
  }
  __shared__ float lds[NTHREADS / 64][4];
  int lane = threadIdx.x & 63, wid = threadIdx.x >> 6;
  if (lane == 0) { lds[wid][0] = v0; lds[wid][1] = v1; lds[wid][2] = v2; lds[wid][3] = v3; }
  __syncthreads();
  if (threadIdx.x == 0) {
    float r0 = 0, r1 = 0, r2 = 0, r3 = 0;
    #pragma unroll
    for (int w = 0; w < NTHREADS / 64; ++w) {
      r0 += lds[w][0]; r1 += lds[w][1]; r2 += lds[w][2]; r3 += lds[w][3];
    }
    dst[0] = r0; dst[1] = r1; dst[2] = r2; dst[3] = r3;
  }
}

__global__ __launch_bounds__(NTHREADS) void yolo_pass(
    const float* __restrict__ yp, const float* __restrict__ yt,
    const float* __restrict__ anch, float* __restrict__ ws)
{
  const int bx = blockIdx.x;
  if (bx >= NB_BLK) {
    // ---------- pass A: uniform BCE over every element, fully coalesced ----------
    float sh = 0.f, sl = 0.f;
    for (int v = (bx - NB_BLK) * NTHREADS + threadIdx.x; v < TOTV;
         v += NA_BLK * NTHREADS) {
      float4 p4 = ((const float4*)yp)[v];
      float4 t4 = ((const float4*)yt)[v];
      #pragma unroll
      for (int k = 0; k < 4; ++k) {
        float x = (&p4.x)[k], t = (&t4.x)[k];
        float u = __expf(-fabsf(x));
        sh += fmaxf(x, 0.0f) - x * t;
        sl += __log2f(1.0f + u);        // * ln2 hoisted to finalize
      }
    }
    // reduce {sh, sl} -> 2 floats
    for (int off = 32; off > 0; off >>= 1) {
      sh += __shfl_down(sh, off); sl += __shfl_down(sl, off);
    }
    __shared__ float lds[NTHREADS / 64][2];
    int lane = threadIdx.x & 63, wid = threadIdx.x >> 6;
    if (lane == 0) { lds[wid][0] = sh; lds[wid][1] = sl; }
    __syncthreads();
    if (threadIdx.x == 0) {
      float r0 = 0, r1 = 0;
      #pragma unroll
      for (int w = 0; w < NTHREADS / 64; ++w) { r0 += lds[w][0]; r1 += lds[w][1]; }
      ws[(bx - NB_BLK) * 2 + 0] = r0;
      ws[(bx - NB_BLK) * 2 + 1] = r1;
    }
  } else {
    // ---------- pass B: one thread per cell, channels 0..4 only ----------
    const int b = bx / NB_BLK_PB, chunk = bx % NB_BLK_PB;
    const int cell = chunk * NTHREADS + threadIdx.x;
    float s1 = 0.f, s2 = 0.f, b5 = 0.f, bo = 0.f;
    if (cell < NCELL) {
      const float* pp = yp + ((size_t)b * NCELL + cell) * DD;
      const float* tt = yt + ((size_t)b * NCELL + cell) * DD;
      float x0 = pp[0], x1 = pp[1], x2 = pp[2], x3 = pp[3], x4 = pp[4];
      float t0 = tt[0], t1 = tt[1], t2 = tt[2], t3 = tt[3], t4 = tt[4];
      int gi = cell / (GG * AA);          // meshgrid 'ij' dim-1
      int gj = (cell / AA) % GG;          // dim-2
      int a  = cell % AA;
      float aw = anch[a * 2 + 0], ah = anch[a * 2 + 1];
      float d0 = (t0 * (float)GG - (float)gi) - fast_sig(x0);
      float d1 = (t1 * (float)GG - (float)gj) - fast_sig(x1);
      float w2 = (t2 > 0.f) ? (__logf(t2) - __logf(aw)) : 0.f;  // log(t2/aw)
      float w3 = (t3 > 0.f) ? (__logf(t3) - __logf(ah)) : 0.f;
      float d2 = w2 - fast_sig(x2);
      float d3 = w3 - fast_sig(x3);
      s1 = (d0 * d0 + d1 * d1 + d2 * d2 + d3 * d3) * t4;
      s2 = t4;
      float b4 = fast_bce(x4, t4);
      b5 = fast_bce(x0, t0) + fast_bce(x1, t1) + fast_bce(x2, t2) + fast_bce(x3, t3) + b4;
      bo = b4;
    }
    block_reduce4(s1, s2, b5, bo, ws + NA_BLK * 2 + bx * 4);
  }
}

__global__ __launch_bounds__(256) void yolo_fin(
    const float* __restrict__ ws, float* __restrict__ out)
{
  const int tid = threadIdx.x;
  float sh = 0.f, sl = 0.f, b5 = 0.f, bo = 0.f;
  for (int i = tid; i < NA_BLK; i += 256) { sh += ws[i * 2]; sl += ws[i * 2 + 1]; }
  const float* pb = ws + NA_BLK * 2;
  for (int i = tid; i < NB_BLK; i += 256) { b5 += pb[i * 4 + 2]; bo += pb[i * 4 + 3]; }
  for (int off = 32; off > 0; off >>= 1) {
    sh += __shfl_down(sh, off); sl += __shfl_down(sl, off);
    b5 += __shfl_down(b5, off); bo += __shfl_down(bo, off);
  }
  __shared__ float red[4][4];
  int lane = tid & 63, wid = tid >> 6;
  if (lane == 0) { red[wid][0] = sh; red[wid][1] = sl; red[wid][2] = b5; red[wid][3] = bo; }
  __syncthreads();
  __shared__ float coef;
  if (tid == 0) {
    float SH = 0, SL = 0, B5 = 0, BO = 0;
    #pragma unroll
    for (int w = 0; w < 4; ++w) {
      SH += red[w][0]; SL += red[w][1]; B5 += red[w][2]; BO += red[w][3];
    }
    float all = SH + LN2 * SL;     // BCE sum over all 85 channels
    float cls = all - B5;          // classes only (c >= 5)
    const float ncls = (float)BB * (float)NCELL * 80.0f;   // 10,383,360
    const float nobj = (float)BB * (float)NCELL;           // 129,792
    coef = 0.5f * cls / ncls + BO / nobj;
  }
  __syncthreads();
  if (tid < BB) {
    const float* pb2 = ws + NA_BLK * 2;
    float s1 = 0.f, s2 = 0.f;
    for (int j = 0; j < NB_BLK_PB; ++j) {
      int idx = (tid * NB_BLK_PB + j) * 4;
      s1 += pb2[idx + 0]; s2 += pb2[idx + 1];
    }
    out[tid] = 2.0f * s1 + coef * s2;
  }
}

extern "C" void kernel_launch(void* const* d_in, const int* in_sizes, int n_in,
                              void* d_out, int out_size, void* d_ws, size_t ws_size,
                              hipStream_t stream) {
  const float* yp   = (const float*)d_in[0];
  const float* yt   = (const float*)d_in[1];
  const float* anch = (const float*)d_in[2];
  float* out = (float*)d_out;
  float* ws  = (float*)d_ws;     // needs (2048*2 + 512*4)*4 = 24 KB

  yolo_pass<<<NB_BLK + NA_BLK, NTHREADS, 0, stream>>>(yp, yt, anch, ws);
  yolo_fin<<<1, 256, 0, stream>>>(ws, out);
}